// Round 1
// baseline (17.939 us; speedup 1.0000x reference)
//
#include <hip/hip_runtime.h>
#include <math.h>

constexpr int NV  = 10;   // n_vars
constexpr int NB  = 5;    // n_basis = 1 + 2*K_MAX
constexpr int DD  = 32;   // D
constexpr int BLK = 256;
constexpr int ROWP = 12;  // padded L row (16B-aligned rows: 12*4=48B)

__global__ __launch_bounds__(BLK) void nxro_fused(
    const float* __restrict__ x,   // [B,10]
    const float* __restrict__ t,   // [B]
    const float* __restrict__ L,   // [5,10,10]
    const float* __restrict__ wq,  // [32]
    const float* __restrict__ wk,  // [32]
    const float* __restrict__ wv,  // [32]
    const float* __restrict__ wo,  // [32]
    const float* __restrict__ aw,  // [5]
    float* __restrict__ out,       // [B,10]
    int B)
{
    __shared__ float4 sstage4[BLK * NV / 4];          // 2560 floats = 10240 B
    __shared__ __align__(16) float sL[NB * NV * ROWP]; // 600 floats, padded rows
    __shared__ float saw[NB];
    __shared__ float sconst[2];                        // c = wq.wk/sqrt(D), g = wv.wo

    float* sstage = reinterpret_cast<float*>(sstage4);
    const int tid = threadIdx.x;
    const long long base  = (long long)blockIdx.x * BLK;
    const long long nelem = (long long)B * NV;

    // ---- stage L_basis (padded) ----
    for (int i = tid; i < NB * NV * ROWP; i += BLK) {
        int row = i / ROWP, col = i % ROWP;
        sL[i] = (col < NV) ? L[row * NV + col] : 0.f;
    }
    if (tid < NB) saw[tid] = aw[tid];
    if (tid == 0) {
        float qk = 0.f, vo = 0.f;
        #pragma unroll
        for (int d = 0; d < DD; ++d) {
            qk = fmaf(wq[d], wk[d], qk);
            vo = fmaf(wv[d], wo[d], vo);
        }
        sconst[0] = qk * 0.17677669529663687f;  // 1/sqrt(32)
        sconst[1] = vo;
    }

    // ---- coalesced float4 load of this block's x rows ----
    {
        const float4* xg = reinterpret_cast<const float4*>(x + base * NV);
        const long long n4 = (nelem - base * NV) / 4;  // remaining float4s
        #pragma unroll
        for (int i = tid; i < BLK * NV / 4; i += BLK)
            sstage4[i] = (i < n4) ? xg[i] : make_float4(0.f, 0.f, 0.f, 0.f);
    }
    __syncthreads();

    const long long b = base + tid;
    float res[NV];
    bool active = (b < (long long)B);
    if (active) {
        float xv[NV];
        #pragma unroll
        for (int v = 0; v < NV; ++v) xv[v] = sstage[tid * NV + v];
        const float tt = t[b];

        // Fourier embedding [1, cos(wt), sin(wt), cos(2wt), sin(2wt)]
        float emb0 = 1.f, emb1, emb2, emb3, emb4;
        sincosf(6.283185307179586f * tt, &emb2, &emb1);
        sincosf(12.566370614359172f * tt, &emb4, &emb3);
        const float emb[NB] = {emb0, emb1, emb2, emb3, emb4};

        const float c = sconst[0];
        const float g = sconst[1];

        // dxdt[u] = sum_k emb[k] * sum_v L[k,u,v] * x[v]
        float dxdt[NV];
        #pragma unroll
        for (int u = 0; u < NV; ++u) dxdt[u] = 0.f;
        #pragma unroll
        for (int k = 0; k < NB; ++k) {
            const float ek = emb[k];
            #pragma unroll
            for (int u = 0; u < NV; ++u) {
                const float4* row4 =
                    reinterpret_cast<const float4*>(&sL[(k * NV + u) * ROWP]);
                float4 r0 = row4[0], r1 = row4[1], r2 = row4[2];
                float acc = 0.f;
                acc = fmaf(r0.x, xv[0], acc); acc = fmaf(r0.y, xv[1], acc);
                acc = fmaf(r0.z, xv[2], acc); acc = fmaf(r0.w, xv[3], acc);
                acc = fmaf(r1.x, xv[4], acc); acc = fmaf(r1.y, xv[5], acc);
                acc = fmaf(r1.z, xv[6], acc); acc = fmaf(r1.w, xv[7], acc);
                acc = fmaf(r2.x, xv[8], acc); acc = fmaf(r2.y, xv[9], acc);
                dxdt[u] = fmaf(ek, acc, dxdt[u]);
            }
        }

        // alpha = sigmoid(emb . alpha_w)
        float z = 0.f;
        #pragma unroll
        for (int k = 0; k < NB; ++k) z = fmaf(emb[k], saw[k], z);
        const float alpha = 1.f / (1.f + __expf(-z));
        const float ga = g * alpha;

        // masked attention: row v attends to {0, 1, v} (v<2: {0,1})
        const float x0 = xv[0], x1 = xv[1];
        #pragma unroll
        for (int v = 0; v < NV; ++v) {
            const float s0 = xv[v] * x0 * c;
            const float s1 = xv[v] * x1 * c;
            float w;
            if (v < 2) {
                const float m = fmaxf(s0, s1);
                const float e0 = __expf(s0 - m), e1 = __expf(s1 - m);
                w = fmaf(e0, x0, e1 * x1) / (e0 + e1);
            } else {
                const float sv = xv[v] * xv[v] * c;
                const float m = fmaxf(fmaxf(s0, s1), sv);
                const float e0 = __expf(s0 - m), e1 = __expf(s1 - m),
                            ev = __expf(sv - m);
                w = fmaf(e0, x0, fmaf(e1, x1, ev * xv[v])) / (e0 + e1 + ev);
            }
            res[v] = fmaf(w, ga, dxdt[v]);
        }
    }
    __syncthreads();   // everyone done with their x row in sstage

    if (active) {
        #pragma unroll
        for (int v = 0; v < NV; ++v) sstage[tid * NV + v] = res[v];
    }
    __syncthreads();

    // ---- coalesced float4 store ----
    {
        float4* og = reinterpret_cast<float4*>(out + base * NV);
        const long long n4 = (nelem - base * NV) / 4;
        #pragma unroll
        for (int i = tid; i < BLK * NV / 4; i += BLK)
            if (i < n4) og[i] = sstage4[i];
    }
}

extern "C" void kernel_launch(void* const* d_in, const int* in_sizes, int n_in,
                              void* d_out, int out_size, void* d_ws, size_t ws_size,
                              hipStream_t stream) {
    const float* x  = (const float*)d_in[0];
    const float* t  = (const float*)d_in[1];
    const float* L  = (const float*)d_in[2];
    const float* wq = (const float*)d_in[3];
    const float* wk = (const float*)d_in[4];
    const float* wv = (const float*)d_in[5];
    const float* wo = (const float*)d_in[6];
    const float* aw = (const float*)d_in[7];
    float* out = (float*)d_out;
    const int B = in_sizes[1];  // t_years element count

    const int grid = (B + BLK - 1) / BLK;
    nxro_fused<<<grid, BLK, 0, stream>>>(x, t, L, wq, wk, wv, wo, aw, out, B);
}

// Round 2
// 14.491 us; speedup vs baseline: 1.2379x; 1.2379x over previous
//
#include <hip/hip_runtime.h>
#include <math.h>

constexpr int NV  = 10;   // n_vars
constexpr int NB  = 5;    // n_basis = 1 + 2*K_MAX
constexpr int DD  = 32;   // D
constexpr int BLK = 256;

__global__ __launch_bounds__(BLK) void nxro_fused(
    const float* __restrict__ x,   // [B,10]
    const float* __restrict__ t,   // [B]
    const float* __restrict__ L,   // [5,10,10]
    const float* __restrict__ wq,  // [32]
    const float* __restrict__ wk,  // [32]
    const float* __restrict__ wv,  // [32]
    const float* __restrict__ wo,  // [32]
    const float* __restrict__ aw,  // [5]
    float* __restrict__ out,       // [B,10]
    int B)
{
    __shared__ float4 sstage4[BLK * NV / 4];  // 2560 floats = 10240 B
    __shared__ float sconst[2 + NB];          // c, g, alpha_w[5]

    float* sstage = reinterpret_cast<float*>(sstage4);
    const int tid = threadIdx.x;
    const long long base  = (long long)blockIdx.x * BLK;
    const long long nelem = (long long)B * NV;

    if (tid == 0) {
        float qk = 0.f, vo = 0.f;
        #pragma unroll
        for (int d = 0; d < DD; ++d) {
            qk = fmaf(wq[d], wk[d], qk);
            vo = fmaf(wv[d], wo[d], vo);
        }
        sconst[0] = qk * 0.17677669529663687f;  // (wq.wk)/sqrt(32)
        sconst[1] = vo;                          // wv.wo
    }
    if (tid < NB) sconst[2 + tid] = aw[tid];

    // ---- coalesced float4 load of this block's x rows into LDS ----
    {
        const float4* xg = reinterpret_cast<const float4*>(x + base * NV);
        const long long n4 = (nelem - base * NV) / 4;
        #pragma unroll
        for (int i = tid; i < BLK * NV / 4; i += BLK)
            sstage4[i] = (i < n4) ? xg[i] : make_float4(0.f, 0.f, 0.f, 0.f);
    }
    __syncthreads();

    const long long b = base + tid;
    const bool active = (b < (long long)B);
    float res[NV];
    if (active) {
        float xv[NV];
        #pragma unroll
        for (int v = 0; v < NV; ++v) xv[v] = sstage[tid * NV + v];
        const float tt = t[b];

        // Fourier embedding via HW sin/cos (input in REVOLUTIONS):
        // emb = [1, cos(2pi t), sin(2pi t), cos(4pi t), sin(4pi t)], t in [0,1)
        const float t2 = tt + tt;
        const float emb[NB] = {
            1.f,
            __builtin_amdgcn_cosf(tt),
            __builtin_amdgcn_sinf(tt),
            __builtin_amdgcn_cosf(t2),
            __builtin_amdgcn_sinf(t2)
        };

        const float c = sconst[0];
        const float g = sconst[1];

        // dxdt[u] = sum_k emb[k] * (L_k x)[u]
        // L indexed by compile-time constants, uniform across the wave ->
        // scalar (SMEM) loads; v_fma with one SGPR operand.
        float dxdt[NV];
        #pragma unroll
        for (int u = 0; u < NV; ++u) dxdt[u] = 0.f;
        #pragma unroll
        for (int k = 0; k < NB; ++k) {
            const float ek = emb[k];
            #pragma unroll
            for (int u = 0; u < NV; ++u) {
                const float* __restrict__ Lr = L + (k * NV + u) * NV;
                float acc = Lr[0] * xv[0];
                #pragma unroll
                for (int v = 1; v < NV; ++v)
                    acc = fmaf(Lr[v], xv[v], acc);
                dxdt[u] = fmaf(ek, acc, dxdt[u]);
            }
        }

        // alpha = sigmoid(emb . alpha_w)
        float z = 0.f;
        #pragma unroll
        for (int k = 0; k < NB; ++k) z = fmaf(emb[k], sconst[2 + k], z);
        const float alpha = 1.f / (1.f + __expf(-z));
        const float ga = g * alpha;

        // masked attention: row v attends to {0, 1, v} (v<2: {0,1})
        const float x0 = xv[0], x1 = xv[1];
        #pragma unroll
        for (int v = 0; v < NV; ++v) {
            const float s0 = xv[v] * x0 * c;
            const float s1 = xv[v] * x1 * c;
            float w;
            if (v < 2) {
                const float m = fmaxf(s0, s1);
                const float e0 = __expf(s0 - m), e1 = __expf(s1 - m);
                w = fmaf(e0, x0, e1 * x1) / (e0 + e1);
            } else {
                const float sv = xv[v] * xv[v] * c;
                const float m = fmaxf(fmaxf(s0, s1), sv);
                const float e0 = __expf(s0 - m), e1 = __expf(s1 - m),
                            ev = __expf(sv - m);
                w = fmaf(e0, x0, fmaf(e1, x1, ev * xv[v])) / (e0 + e1 + ev);
            }
            res[v] = fmaf(w, ga, dxdt[v]);
        }
        // own-row write-back (no cross-thread hazard vs own-row reads above)
        #pragma unroll
        for (int v = 0; v < NV; ++v) sstage[tid * NV + v] = res[v];
    }
    __syncthreads();

    // ---- coalesced float4 store ----
    {
        float4* og = reinterpret_cast<float4*>(out + base * NV);
        const long long n4 = (nelem - base * NV) / 4;
        #pragma unroll
        for (int i = tid; i < BLK * NV / 4; i += BLK)
            if (i < n4) og[i] = sstage4[i];
    }
}

extern "C" void kernel_launch(void* const* d_in, const int* in_sizes, int n_in,
                              void* d_out, int out_size, void* d_ws, size_t ws_size,
                              hipStream_t stream) {
    const float* x  = (const float*)d_in[0];
    const float* t  = (const float*)d_in[1];
    const float* L  = (const float*)d_in[2];
    const float* wq = (const float*)d_in[3];
    const float* wk = (const float*)d_in[4];
    const float* wv = (const float*)d_in[5];
    const float* wo = (const float*)d_in[6];
    const float* aw = (const float*)d_in[7];
    float* out = (float*)d_out;
    const int B = in_sizes[1];  // t_years element count

    const int grid = (B + BLK - 1) / BLK;
    nxro_fused<<<grid, BLK, 0, stream>>>(x, t, L, wq, wk, wv, wo, aw, out, B);
}